// Round 11
// baseline (204.662 us; speedup 1.0000x reference)
//
#include <hip/hip_runtime.h>
#include <math.h>

#define HW (128*128)

typedef short short8 __attribute__((ext_vector_type(8)));
typedef float floatx4 __attribute__((ext_vector_type(4)));
typedef unsigned int uintx4 __attribute__((ext_vector_type(4)));
typedef _Float16 half2v __attribute__((ext_vector_type(2)));
typedef _Float16 half8v __attribute__((ext_vector_type(8)));

#define MFMA(a,b,c)   __builtin_amdgcn_mfma_f32_16x16x32_bf16((a),(b),(c),0,0,0)
#define MFMA16(a,b,c) __builtin_amdgcn_mfma_f32_16x16x32_f16((a),(b),(c),0,0,0)

union V16 { uintx4 u; half2v h2[4]; half8v h8; };

// ---------------- workspace layout ----------------
// FULL tier: [tin fp16 NHWC 16MB][wt3h fp16 main wts][wmtA fp16 offset wts]
#define WT3_ELEMS   (9*3*4*64*8)         // [kk][ks][quad][o][i], c=ks*32+quad*8+i
#define WMTA_ELEMS  (19*2*4*16*8)        // [kt][n][quad][m15][i]  (19456)
#define WMT_ELEMS   (594*27)             // MID tier fp32 [(c*9+j)*27+oc]
#define TIN_BYTES   ((size_t)8*HW*64*2)  // 16 MB
#define WT3_OFF     TIN_BYTES
#define WMTA_OFF    (WT3_OFF + (size_t)WT3_ELEMS*2)
#define WS_FULL     (WMTA_OFF + (size_t)WMTA_ELEMS*2)
// MID tier (R5 kernel): [wt3 bf16][wmt fp32]
#define WS_MID      ((size_t)WT3_ELEMS*2 + (size_t)WMT_ELEMS*4)

static __device__ __forceinline__ unsigned short f2bf(float x) {
    unsigned u = __float_as_uint(x);
    unsigned r = u + 0x7FFFu + ((u >> 16) & 1u);
    return (unsigned short)(r >> 16);
}

static __device__ __forceinline__ unsigned cvt_pk_bf16(float lo, float hi) {
    unsigned r;
    asm("v_cvt_pk_bf16_f32 %0, %1, %2" : "=v"(r) : "v"(lo), "v"(hi));
    return r;
}

// ---------------- prep: fp16 weights (FULL tier: wt3h + wmtA) ----------------
__global__ __launch_bounds__(256) void prep_w16(
    const float* __restrict__ weight, const float* __restrict__ w_om,
    _Float16* __restrict__ wt3, _Float16* __restrict__ wmtA)
{
    int t = blockIdx.x * 256 + threadIdx.x;
    if (t < WT3_ELEMS) {
        int i = t & 7;  int u = t >> 3;
        int o = u & 63; u >>= 6;
        int quad = u & 3; u >>= 2;
        int ks = u % 3, kk = u / 3;
        int c = ks * 32 + quad * 8 + i;
        float v = (c < 66) ? weight[o * 594 + c * 9 + kk] : 0.0f;
        wt3[t] = (_Float16)v;
    } else if (t < WT3_ELEMS + WMTA_ELEMS) {
        int t2 = t - WT3_ELEMS;
        int i = t2 & 7;  int u = t2 >> 3;
        int m15 = u & 15; u >>= 4;
        int quad = u & 3; u >>= 2;
        int n = u & 1;    int kt = u >> 1;
        int o = 16 * n + m15;
        float v = 0.0f;
        if (o < 27) {
            if (kt < 18) {
                int j = kt >> 1, c = (kt & 1) * 32 + quad * 8 + i;
                v = w_om[o * 594 + c * 9 + j];
            } else {
                int q = quad * 8 + i;
                if (q < 18) {
                    int j = q >> 1, c = 64 + (q & 1);
                    v = w_om[o * 594 + c * 9 + j];
                }
            }
        }
        wmtA[t2] = (_Float16)v;
    }
}

// ---------------- prep: NCHW fp32 -> NHWC fp16 transpose ----------------
__global__ __launch_bounds__(256) void prep_t(
    const float* __restrict__ in, _Float16* __restrict__ t_out)
{
    __shared__ float s[64][129];
    const int y = blockIdx.x, b = blockIdx.y;
    const int tid = threadIdx.x, lane = tid & 63, w = tid >> 6;
    const float* src = in + (size_t)b * 64 * HW + y * 128;
#pragma unroll
    for (int i = 0; i < 16; ++i) {
        int c = w * 16 + i;
        s[c][lane]      = src[(size_t)c * HW + lane];
        s[c][lane + 64] = src[(size_t)c * HW + lane + 64];
    }
    __syncthreads();
    _Float16* dst = t_out + ((size_t)b * HW + (size_t)y * 128) * 64;
    const int c = lane, x0 = w * 32;
#pragma unroll
    for (int xx = 0; xx < 32; ++xx) {
        int x = x0 + xx;
        dst[(size_t)x * 64 + c] = (_Float16)s[c][x];
    }
}

// ---------------- prep: weights (bf16+fp32, MID tier) ----------------
__global__ __launch_bounds__(256) void prep_w(
    const float* __restrict__ weight, const float* __restrict__ w_om,
    unsigned short* __restrict__ wt3, float* __restrict__ wmt)
{
    int t = blockIdx.x * 256 + threadIdx.x;
    if (t < WT3_ELEMS) {
        int i = t & 7;  int u = t >> 3;
        int o = u & 63; u >>= 6;
        int quad = u & 3; u >>= 2;
        int ks = u % 3, kk = u / 3;
        int c = ks * 32 + quad * 8 + i;
        float v = (c < 66) ? weight[o * 594 + c * 9 + kk] : 0.0f;
        wt3[t] = f2bf(v);
    } else if (t < WT3_ELEMS + WMT_ELEMS) {
        int t2 = t - WT3_ELEMS;
        int oc = t2 % 27, ck = t2 / 27;
        wmt[t2] = w_om[oc * 594 + ck];
    }
}

// Round 2:  XCD-pinning remap (FETCH 268MB -> 18.5MB, verified).
// Round 6:  NHWC fp16 shadow input, dwordx4 Phase-B gathers (274 -> 214us).
// Round 7:  Phase A on matrix cores (214 -> 171us).
// Round 10: spill fix, (256,8)->(256,4): VGPR 32->64, WRITE 199->46.6MB
//   (=logical), FETCH->8.9MB, 171 -> 119.6us.
// Round 11: raise the VGPR cap again. Observed compiler heuristic across
//   R5-R10: allocated VGPR = cap/2 ((256,8)->32, (256,6)->40, (256,4)->64).
//   At 64 regs the scheduler can't keep two taps' gathers (32 regs) in
//   flight across the MFMA block -> per-tap serial chain ~700cy, 75% stall
//   (VALUBusy 18%, MfmaUtil 6.5%, HBM 6%). (256,2) -> cap 256 -> predicted
//   alloc ~128 -> 4 waves/SIMD (= today's measured ~12.5 waves/CU, no real
//   TLP loss) + register room for the already-unrolled tap loop to
//   software-pipeline automatically. Tell-tale: VGPR must rise >=96 and
//   WRITE_SIZE must stay 46.6MB (growth = spills -> revert).
__global__ __launch_bounds__(256, 2) void dcn_hybrid11(
    const _Float16* __restrict__ t_in,
    const _Float16* __restrict__ wt3h,
    const _Float16* __restrict__ wmtA,
    const float* __restrict__ bias,
    const float* __restrict__ b_om,
    float* __restrict__ out)
{
    __shared__ float s_om[32 * 65];                                    // 8320 B
    __shared__ float s_offh[9 * 64], s_offw[9 * 64], s_maskf[9 * 64];  // 6912 B

    const int tid  = threadIdx.x;
    const int lane = tid & 63;
    const int w    = tid >> 6;
    const int wu   = __builtin_amdgcn_readfirstlane(w);
    const int m15  = lane & 15;
    const int quad = lane >> 4;

    // ---- XCD-pinning remap
    const int L   = blockIdx.x + 2 * (blockIdx.y + 128 * blockIdx.z);
    const int b   = L & 7;
    const int r   = L >> 3;
    const int ho  = r >> 1;
    const int wo0 = (r & 1) * 64;

    const float invH = 1.0f / 128.0f;

    const int pixL = wu * 16 + m15;          // this lane's pixel (Phase A+B)
    const int wob  = wo0 + pixL;

    const _Float16* tinb = t_in + (size_t)b * HW * 64;
    const _Float16* tinq = tinb + quad * 8;

    // ---- 9 fixed-tap addresses / validity for pixel (ho, wob)
    int   ta[9];
    float ok9[9];
#pragma unroll
    for (int j = 0; j < 9; ++j) {
        int y = ho - 1 + j / 3;
        int x = wob - 1 + j % 3;
        bool ok = ((unsigned)y < 128u) && ((unsigned)x < 128u);
        int yc = min(max(y, 0), 127), xc = min(max(x, 0), 127);
        ta[j]  = yc * 128 + xc;
        ok9[j] = ok ? 1.0f : 0.0f;
    }

    // ---------------- Phase A: offset conv via f16 MFMA ----------------
    floatx4 a0 = (floatx4){0.f, 0.f, 0.f, 0.f};
    floatx4 a1 = (floatx4){0.f, 0.f, 0.f, 0.f};

#pragma unroll
    for (int j = 0; j < 9; ++j) {
        _Float16 okh = (_Float16)ok9[j];
        half2v okh2 = {okh, okh};
#pragma unroll
        for (int h = 0; h < 2; ++h) {
            V16 bb;
            bb.u = *(const uintx4*)(tinq + (size_t)ta[j] * 64 + h * 32);
#pragma unroll
            for (int rr = 0; rr < 4; ++rr) bb.h2[rr] = bb.h2[rr] * okh2;
            const int kt = j * 2 + h;
            const _Float16* ap = wmtA + (size_t)((kt * 2) * 4 + quad) * 128 + m15 * 8;
            half8v A0 = *(const half8v*)ap;
            half8v A1 = *(const half8v*)(ap + 512);
            a0 = MFMA16(A0, bb.h8, a0);
            a1 = MFMA16(A1, bb.h8, a1);
        }
    }
    {   // coord K-tile (kt=18): ch64 = y/H, ch65 = x/H-0.5, masked
        V16 bb;
#pragma unroll
        for (int rr = 0; rr < 4; ++rr) {
            float ve = 0.f, vo = 0.f;
            int j = quad * 4 + rr;           // q = quad*8+2rr -> j = q>>1
            if (j < 9) {
                int y = ho - 1 + j / 3;
                int x = wob - 1 + j % 3;
                bool ok = ((unsigned)y < 128u) && ((unsigned)x < 128u);
                ve = ok ? y * invH : 0.f;
                vo = ok ? (x * invH - 0.5f) : 0.f;
            }
            bb.h2[rr] = (half2v){(_Float16)ve, (_Float16)vo};
        }
        const _Float16* ap = wmtA + (size_t)((18 * 2) * 4 + quad) * 128 + m15 * 8;
        half8v A0 = *(const half8v*)ap;
        half8v A1 = *(const half8v*)(ap + 512);
        a0 = MFMA16(A0, bb.h8, a0);
        a1 = MFMA16(A1, bb.h8, a1);
    }

    // stage om to LDS: s_om[oc][pix] (padded row 65)
#pragma unroll
    for (int rr = 0; rr < 4; ++rr) {
        s_om[(quad * 4 + rr) * 65 + pixL]      = a0[rr];
        s_om[(16 + quad * 4 + rr) * 65 + pixL] = a1[rr];
    }
    __syncthreads();

    // ---- idx/mask epilogue (nt stores) + fp32 offsets/mask into LDS
    {
        float* out_idx = out + (size_t)8 * 64 * HW;
        float* out_msk = out_idx + (size_t)8 * 18 * HW;
        const int wo = wo0 + lane;
        const int p  = ho * 128 + wo;
        const float hg = ho * invH;
        const float wg = wo * invH - 0.5f;
        int oc0 = wu * 7;
        int noc = (wu == 3) ? 6 : 7;
        for (int t = 0; t < noc; ++t) {
            int oc = oc0 + t;
            float s = b_om[oc] + s_om[oc * 65 + lane];
            if (oc < 9) {
                __builtin_nontemporal_store(hg + (float)(oc / 3 - 1) + s,
                    &out_idx[((size_t)b * 18 + oc) * HW + p]);
                if (oc & 1) s_offw[(oc >> 1) * 64 + lane] = s;
                else        s_offh[(oc >> 1) * 64 + lane] = s;
            } else if (oc < 18) {
                __builtin_nontemporal_store(wg + (float)((oc - 9) % 3 - 1) + s,
                    &out_idx[((size_t)b * 18 + oc) * HW + p]);
                if (oc & 1) s_offw[(oc >> 1) * 64 + lane] = s;
                else        s_offh[(oc >> 1) * 64 + lane] = s;
            } else {
                float mkv = 1.0f / (1.0f + __expf(-s));
                __builtin_nontemporal_store(mkv,
                    &out_msk[((size_t)b * 9 + (oc - 18)) * HW + p]);
                s_maskf[(oc - 18) * 64 + lane] = mkv;
            }
        }
    }
    __syncthreads();   // offsets/mask ready

    // ---------------- Phase B: NHWC fp16 gathers + f16 MFMA (proven) ------
    floatx4 acc[4];
#pragma unroll
    for (int t = 0; t < 4; ++t) acc[t] = (floatx4){0.f, 0.f, 0.f, 0.f};

    const int hom1 = ho - 1;

#pragma unroll
    for (int kk = 0; kk < 9; ++kk) {
        float offh = s_offh[kk * 64 + pixL];
        float offw = s_offw[kk * 64 + pixL];
        float mval = s_maskf[kk * 64 + pixL];

        float ph = offh + (float)(kk / 3) + (float)hom1;
        float pw = offw + (float)(kk % 3) + (float)(wob - 1);
        float h0f = floorf(ph), w0f = floorf(pw);
        int h0 = (int)h0f, w0 = (int)w0f;
        int h1 = h0 + 1, w1 = w0 + 1;
        float lh = ph - h0f, lw = pw - w0f;
        float hh = 1.0f - lh, hwp = 1.0f - lw;
        bool okh0 = (unsigned)h0 < 128u, okh1 = (unsigned)h1 < 128u;
        bool okw0 = (unsigned)w0 < 128u, okw1 = (unsigned)w1 < 128u;
        float w00 = (okh0 && okw0) ? hh * hwp * mval : 0.0f;
        float w01 = (okh0 && okw1) ? hh * lw  * mval : 0.0f;
        float w10 = (okh1 && okw0) ? lh * hwp * mval : 0.0f;
        float w11 = (okh1 && okw1) ? lh * lw  * mval : 0.0f;
        int h0c = min(max(h0, 0), 127), h1c = min(max(h1, 0), 127);
        int w0c = min(max(w0, 0), 127), w1c = min(max(w1, 0), 127);
        int o00 = h0c * 128 + w0c, o01 = h0c * 128 + w1c;
        int o10 = h1c * 128 + w0c, o11 = h1c * 128 + w1c;

        V16 A00, A01, A10, A11, B00, B01, B10, B11;
        A00.u = *(const uintx4*)(tinq + (size_t)o00 * 64);
        A01.u = *(const uintx4*)(tinq + (size_t)o01 * 64);
        A10.u = *(const uintx4*)(tinq + (size_t)o10 * 64);
        A11.u = *(const uintx4*)(tinq + (size_t)o11 * 64);
        B00.u = *(const uintx4*)(tinq + (size_t)o00 * 64 + 32);
        B01.u = *(const uintx4*)(tinq + (size_t)o01 * 64 + 32);
        B10.u = *(const uintx4*)(tinq + (size_t)o10 * 64 + 32);
        B11.u = *(const uintx4*)(tinq + (size_t)o11 * 64 + 32);

        _Float16 h00 = (_Float16)w00, h01 = (_Float16)w01;
        _Float16 h10 = (_Float16)w10, h11 = (_Float16)w11;
        half2v W00 = {h00, h00}, W01 = {h01, h01};
        half2v W10 = {h10, h10}, W11 = {h11, h11};

        V16 b0, b1, b2;
#pragma unroll
        for (int rr = 0; rr < 4; ++rr) {
            b0.h2[rr] = A00.h2[rr] * W00 + A01.h2[rr] * W01
                      + A10.h2[rr] * W10 + A11.h2[rr] * W11;
            b1.h2[rr] = B00.h2[rr] * W00 + B01.h2[rr] * W01
                      + B10.h2[rr] * W10 + B11.h2[rr] * W11;
        }
        float c64 = (w00 + w01) * (h0c * invH) + (w10 + w11) * (h1c * invH);
        float c65 = (w00 + w10) * (w0c * invH - 0.5f) + (w01 + w11) * (w1c * invH - 0.5f);
        b2.u = (uintx4){0u, 0u, 0u, 0u};
        if (quad == 0) b2.h2[0] = (half2v){(_Float16)c64, (_Float16)c65};

        const _Float16* w0p = wt3h + (size_t)(kk * 3) * 2048 + quad * 512;
        const _Float16* w1p = w0p + 2048;
        const _Float16* w2p = w0p + 4096;
#pragma unroll
        for (int t = 0; t < 4; ++t) {
            int o8 = (16 * t + m15) * 8;
            half8v A0 = *(const half8v*)&w0p[o8];
            half8v A1 = *(const half8v*)&w1p[o8];
            half8v A2 = *(const half8v*)&w2p[o8];
            acc[t] = MFMA16(A0, b0.h8, acc[t]);
            acc[t] = MFMA16(A1, b1.h8, acc[t]);
            acc[t] = MFMA16(A2, b2.h8, acc[t]);
        }
    }

    // ---------- epilogue: LDS redistribute -> full-line nt stores ------
    // acc[t][rr] holds o = 16t + quad*4 + rr for pixel pixL (verified R7).
    {
        const size_t rowbase = (size_t)b * 64 * HW + (size_t)ho * 128 + wo0;
        __syncthreads();   // Phase-B LDS reads done
        // half 0: channels 0..31 (t = 0,1)
#pragma unroll
        for (int t = 0; t < 2; ++t)
#pragma unroll
            for (int rr = 0; rr < 4; ++rr)
                s_om[(16 * t + quad * 4 + rr) * 65 + pixL] = acc[t][rr];
        __syncthreads();
#pragma unroll
        for (int k = 0; k < 8; ++k) {
            int o = wu * 8 + k;
            float v = s_om[o * 65 + lane] + bias[o];
            __builtin_nontemporal_store(v, &out[(size_t)o * HW + rowbase + lane]);
        }
        __syncthreads();
        // half 1: channels 32..63 (t = 2,3)
#pragma unroll
        for (int t = 0; t < 2; ++t)
#pragma unroll
            for (int rr = 0; rr < 4; ++rr)
                s_om[(16 * t + quad * 4 + rr) * 65 + pixL] = acc[2 + t][rr];
        __syncthreads();
#pragma unroll
        for (int k = 0; k < 8; ++k) {
            int o = 32 + wu * 8 + k;
            float v = s_om[(o - 32) * 65 + lane] + bias[o];
            __builtin_nontemporal_store(v, &out[(size_t)o * HW + rowbase + lane]);
        }
    }
}

// ---------------- MID tier: R5 kernel (verified), bf16 MFMA ----------------
__global__ __launch_bounds__(256, 4) void dcn_hybrid7(
    const float* __restrict__ input,
    const unsigned short* __restrict__ wt3,
    const float* __restrict__ bias,
    const float* __restrict__ wmt,
    const float* __restrict__ b_om,
    float* __restrict__ out)
{
    __shared__ float s_red[4 * 27 * 64];
    __shared__ float s_offh[9 * 64], s_offw[9 * 64], s_maskf[9 * 64];

    const int tid  = threadIdx.x;
    const int lane = tid & 63;
    const int w    = tid >> 6;
    const int wu   = __builtin_amdgcn_readfirstlane(w);
    const int m15  = lane & 15;
    const int quad = lane >> 4;

    const int L   = blockIdx.x + 2 * (blockIdx.y + 128 * blockIdx.z);
    const int b   = L & 7;
    const int r   = L >> 3;
    const int ho  = r >> 1;
    const int wo0 = (r & 1) * 64;

    const int wo  = wo0 + lane;
    const int p   = ho * 128 + wo;
    const float invH = 1.0f / 128.0f;

    const float* inb = input + (size_t)b * 64 * HW;

    int   a9[9];
    float okf[9], vy[9], vx[9];
#pragma unroll
    for (int j = 0; j < 9; ++j) {
        int y = ho - 1 + j / 3;
        int x = wo - 1 + j % 3;
        bool ok = ((unsigned)y < 128u) && ((unsigned)x < 128u);
        int yc = min(max(y, 0), 127), xc = min(max(x, 0), 127);
        a9[j]  = yc * 128 + xc;
        okf[j] = ok ? 1.0f : 0.0f;
        vy[j]  = ok ? y * invH : 0.0f;
        vx[j]  = ok ? (x * invH - 0.5f) : 0.0f;
    }

    const int nc = (wu < 2) ? 17 : 16;

    float om_part[27];
#pragma unroll
    for (int oc = 0; oc < 27; ++oc) om_part[oc] = 0.0f;

    {
        float va[9], vb[9];
        {
            const float* pc = inb + wu * HW;
#pragma unroll
            for (int j = 0; j < 9; ++j) va[j] = pc[a9[j]] * okf[j];
        }
        for (int i = 0; i < nc; ++i) {
            int c = wu + 4 * i;
            if (i + 1 < nc) {
                int cn = c + 4;
                if (cn < 64) {
                    const float* pc = inb + cn * HW;
#pragma unroll
                    for (int j = 0; j < 9; ++j) vb[j] = pc[a9[j]] * okf[j];
                } else if (cn == 64) {
#pragma unroll
                    for (int j = 0; j < 9; ++j) vb[j] = vy[j];
                } else {
#pragma unroll
                    for (int j = 0; j < 9; ++j) vb[j] = vx[j];
                }
            }
#pragma unroll
            for (int j = 0; j < 9; ++j) {
                const float* wp = wmt + (c * 9 + j) * 27;
#pragma unroll
                for (int oc = 0; oc < 27; ++oc)
                    om_part[oc] = fmaf(va[j], wp[oc], om_part[oc]);
            }
#pragma unroll
            for (int j = 0; j < 9; ++j) va[j] = vb[j];
        }
    }
#pragma unroll
    for (int oc = 0; oc < 27; ++oc)
        s_red[(w * 27 + oc) * 64 + lane] = om_part[oc];
    __syncthreads();

    {
        float* out_idx = out + (size_t)8 * 64 * HW;
        float* out_msk = out_idx + (size_t)8 * 18 * HW;
        const float hg = ho * invH;
        const float wg = wo * invH - 0.5f;
        int oc0 = wu * 7;
        int noc = (wu == 3) ? 6 : 7;
        for (int t = 0; t < noc; ++t) {
            int oc = oc0 + t;
            float s = b_om[oc]
                    + s_red[(0 * 27 + oc) * 64 + lane]
                    + s_red[(1 * 27 + oc) * 64 + lane]
                    + s_red[(2 * 27 + oc) * 64 + lane]
                    + s_red[(3 * 27 + oc) * 64 + lane];
            if (oc < 9) {
                out_idx[((size_t)b * 18 + oc) * HW + p] = hg + (float)(oc / 3 - 1) + s;
                if (oc & 1) s_offw[(oc >> 1) * 64 + lane] = s;
                else        s_offh[(oc >> 1) * 64 + lane] = s;
            } else if (oc < 18) {
                out_idx[((size_t)b * 18 + oc) * HW + p] = wg + (float)((oc - 9) % 3 - 1) + s;
                if (oc & 1) s_offw[(oc >> 1) * 64 + lane] = s;
                else        s_offh[(oc >> 1) * 64 + lane] = s;
            } else {
                float mkv = 1.0f / (1.0f + __expf(-s));
                out_msk[((size_t)b * 9 + (oc - 18)) * HW + p] = mkv;
                s_maskf[(oc - 18) * 64 + lane] = mkv;
            }
        }
    }
    __syncthreads();

    const int pixL = wu * 16 + m15;
    const int wob  = wo0 + pixL;
    const int hom1 = ho - 1;

    floatx4 acc[4];
#pragma unroll
    for (int t = 0; t < 4; ++t) acc[t] = (floatx4){0.f, 0.f, 0.f, 0.f};

    const float* base0 = inb + (size_t)(quad * 8) * HW;
    const float* base1 = base0 + (size_t)32 * HW;

#pragma unroll
    for (int kk = 0; kk < 9; ++kk) {
        float offh = s_offh[kk * 64 + pixL];
        float offw = s_offw[kk * 64 + pixL];
        float mval = s_maskf[kk * 64 + pixL];

        float ph = offh + (float)(kk / 3) + (float)hom1;
        float pw = offw + (float)(kk % 3) + (float)(wob - 1);
        float h0f = floorf(ph), w0f = floorf(pw);
        int h0 = (int)h0f, w0 = (int)w0f;
        int h1 = h0 + 1, w1 = w0 + 1;
        float lh = ph - h0f, lw = pw - w0f;
        float hh = 1.0f - lh, hwp = 1.0f - lw;
        bool okh0 = (unsigned)h0 < 128u, okh1 = (unsigned)h1 < 128u;
        bool okw0 = (unsigned)w0 < 128u, okw1 = (unsigned)w1 < 128u;
        float w00 = (okh0 && okw0) ? hh * hwp * mval : 0.0f;
        float w01 = (okh0 && okw1) ? hh * lw  * mval : 0.0f;
        float w10 = (okh1 && okw0) ? lh * hwp * mval : 0.0f;
        float w11 = (okh1 && okw1) ? lh * lw  * mval : 0.0f;
        int h0c = min(max(h0, 0), 127), h1c = min(max(h1, 0), 127);
        int w0c = min(max(w0, 0), 127), w1c = min(max(w1, 0), 127);
        int o00 = h0c * 128 + w0c, o01 = h0c * 128 + w1c;
        int o10 = h1c * 128 + w0c, o11 = h1c * 128 + w1c;

        unsigned pk0[4], pk1[4];
#pragma unroll
        for (int j = 0; j < 4; ++j) {
            const float* pa = base0 + (size_t)(2 * j) * HW;
            const float* pb = pa + HW;
            float ca = w00 * pa[o00] + w01 * pa[o01] + w10 * pa[o10] + w11 * pa[o11];
            float cb = w00 * pb[o00] + w01 * pb[o01] + w10 * pb[o10] + w11 * pb[o11];
            pk0[j] = cvt_pk_bf16(ca, cb);
            const float* pa1 = base1 + (size_t)(2 * j) * HW;
            const float* pb1 = pa1 + HW;
            float ca1 = w00 * pa1[o00] + w01 * pa1[o01] + w10 * pa1[o10] + w11 * pa1[o11];
            float cb1 = w00 * pb1[o00] + w01 * pb1[o01] + w10 * pb1[o10] + w11 * pb1[o11];
            pk1[j] = cvt_pk_bf16(ca1, cb1);
        }
        union { uintx4 u; short8 s; } b0, b1, b2;
        b0.u = (uintx4){pk0[0], pk0[1], pk0[2], pk0[3]};
        b1.u = (uintx4){pk1[0], pk1[1], pk1[2], pk1[3]};
        float c64 = (w00 + w01) * (h0c * invH) + (w10 + w11) * (h1c * invH);
        float c65 = (w00 + w10) * (w0c * invH - 0.5f) + (w01 + w11) * (w1c * invH - 0.5f);
        unsigned pk2 = (quad == 0) ? cvt_pk_bf16(c64, c65) : 0u;
        b2.u = (uintx4){pk2, 0u, 0u, 0u};

        const unsigned short* w0p = wt3 + (size_t)(kk * 3 + 0) * 2048 + quad * 512;
        const unsigned short* w1p = w0p + 2048;
        const unsigned short* w2p = w0p + 4096;
#pragma unroll
        for (int t = 0; t < 4; ++t) {
            int o8 = (16 * t + m15) * 8;
            short8 A0 = *(const short8*)&w0p[o8];
            short8 A1 = *(const short8*)&w1p[o8];
            short8 A2 = *(const short8*)&w2p[o8];
            acc[t] = MFMA(A0, b0.s, acc[t]);
            acc[t] = MFMA(A1, b1.s, acc[t]);
            acc[t] = MFMA(A2, b2.s, acc[t]);
        }
    }

    {
        size_t pb = (size_t)ho * 128 + wob;
#pragma unroll
        for (int t = 0; t < 4; ++t) {
#pragma unroll
            for (int rr = 0; rr < 4; ++rr) {
                int o = 16 * t + quad * 4 + rr;
                out[((size_t)b * 64 + o) * HW + pb] = acc[t][rr] + bias[o];
            }
        }
    }
}

// ------------------- fallback (no workspace): fp32 baseline -------------------
__global__ __launch_bounds__(256) void dcn_fb(
    const float* __restrict__ input,
    const float* __restrict__ wmain,
    const float* __restrict__ bias,
    const float* __restrict__ wom,
    const float* __restrict__ b_om,
    float* __restrict__ out)
{
    const int wo = blockIdx.x * 64 + threadIdx.x;
    const int ho = blockIdx.y * 4 + threadIdx.y;
    const int b  = blockIdx.z;
    const int p  = ho * 128 + wo;
    const float invH = 1.0f / 128.0f;
    const float* inb = input + (size_t)b * 64 * HW;

    float om[27];
#pragma unroll
    for (int oc = 0; oc < 27; ++oc) om[oc] = b_om[oc];

    for (int c = 0; c < 64; ++c) {
        const float* pc = inb + c * HW;
        float v[9];
#pragma unroll
        for (int kh = 0; kh < 3; ++kh) {
            int y = ho - 1 + kh;
            bool oky = (unsigned)y < 128u;
#pragma unroll
            for (int kw = 0; kw < 3; ++kw) {
                int x = wo - 1 + kw;
                bool ok = oky && ((unsigned)x < 128u);
                v[kh*3+kw] = ok ? pc[y * 128 + x] : 0.0f;
            }
        }
#pragma unroll
        for (int oc = 0; oc < 27; ++oc)
#pragma unroll
            for (int i = 0; i < 9; ++i)
                om[oc] = fmaf(v[i], wom[oc*594 + c*9 + i], om[oc]);
    }
    {
        float v64[9], v65[9];
#pragma unroll
        for (int kh = 0; kh < 3; ++kh) {
            int y = ho - 1 + kh;
            bool oky = (unsigned)y < 128u;
#pragma unroll
            for (int kw = 0; kw < 3; ++kw) {
                int x = wo - 1 + kw;
                bool ok = oky && ((unsigned)x < 128u);
                v64[kh*3+kw] = ok ? y * invH : 0.0f;
                v65[kh*3+kw] = ok ? (x * invH - 0.5f) : 0.0f;
            }
        }
#pragma unroll
        for (int oc = 0; oc < 27; ++oc)
#pragma unroll
            for (int i = 0; i < 9; ++i) {
                om[oc] = fmaf(v64[i], wom[oc*594 + 64*9 + i], om[oc]);
                om[oc] = fmaf(v65[i], wom[oc*594 + 65*9 + i], om[oc]);
            }
    }

    const float hg = ho * invH;
    const float wg = wo * invH - 0.5f;
    float* out_idx = out + (size_t)8 * 64 * HW;
    float* out_msk = out_idx + (size_t)8 * 18 * HW;
#pragma unroll
    for (int cc = 0; cc < 9; ++cc)
        out_idx[((size_t)b*18 + cc)*HW + p] = hg + (float)(cc/3 - 1) + om[cc];
#pragma unroll
    for (int cc = 9; cc < 18; ++cc)
        out_idx[((size_t)b*18 + cc)*HW + p] = wg + (float)((cc-9)%3 - 1) + om[cc];

    float mk[9];
#pragma unroll
    for (int kk = 0; kk < 9; ++kk) {
        mk[kk] = 1.0f / (1.0f + __expf(-om[18+kk]));
        out_msk[((size_t)b*9 + kk)*HW + p] = mk[kk];
    }

    float acc[64];
#pragma unroll
    for (int o = 0; o < 64; ++o) acc[o] = bias[o];

#pragma unroll
    for (int kk = 0; kk < 9; ++kk) {
        float ph = om[2*kk]   + (float)(kk/3) + (float)(ho - 1);
        float pw = om[2*kk+1] + (float)(kk%3) + (float)(wo - 1);
        float h0f = floorf(ph), w0f = floorf(pw);
        int h0 = (int)h0f, w0 = (int)w0f;
        int h1 = h0 + 1, w1 = w0 + 1;
        float lh = ph - h0f, lw = pw - w0f;
        float hh = 1.0f - lh, hwp = 1.0f - lw;
        float m = mk[kk];
        bool okh0 = (unsigned)h0 < 128u, okh1 = (unsigned)h1 < 128u;
        bool okw0 = (unsigned)w0 < 128u, okw1 = (unsigned)w1 < 128u;
        float w00 = (okh0 && okw0) ? hh*hwp*m : 0.0f;
        float w01 = (okh0 && okw1) ? hh*lw*m  : 0.0f;
        float w10 = (okh1 && okw0) ? lh*hwp*m : 0.0f;
        float w11 = (okh1 && okw1) ? lh*lw*m  : 0.0f;
        int h0c = min(max(h0, 0), 127), h1c = min(max(h1, 0), 127);
        int w0c = min(max(w0, 0), 127), w1c = min(max(w1, 0), 127);
        int o00 = h0c*128 + w0c, o01 = h0c*128 + w1c;
        int o10 = h1c*128 + w0c, o11 = h1c*128 + w1c;

        for (int c = 0; c < 64; ++c) {
            const float* pc = inb + c * HW;
            float col = w00*pc[o00] + w01*pc[o01] + w10*pc[o10] + w11*pc[o11];
#pragma unroll
            for (int o = 0; o < 64; ++o)
                acc[o] = fmaf(col, wmain[o*594 + c*9 + kk], acc[o]);
        }
        {
            float y0 = h0c * invH, y1 = h1c * invH;
            float x0 = w0c * invH - 0.5f, x1 = w1c * invH - 0.5f;
            float col64 = (w00 + w01)*y0 + (w10 + w11)*y1;
            float col65 = (w00 + w10)*x0 + (w01 + w11)*x1;
#pragma unroll
            for (int o = 0; o < 64; ++o) {
                acc[o] = fmaf(col64, wmain[o*594 + 64*9 + kk], acc[o]);
                acc[o] = fmaf(col65, wmain[o*594 + 65*9 + kk], acc[o]);
            }
        }
    }

#pragma unroll
    for (int o = 0; o < 64; ++o)
        out[((size_t)b*64 + o)*HW + p] = acc[o];
}

extern "C" void kernel_launch(void* const* d_in, const int* in_sizes, int n_in,
                              void* d_out, int out_size, void* d_ws, size_t ws_size,
                              hipStream_t stream)
{
    const float* input  = (const float*)d_in[0];
    const float* weight = (const float*)d_in[1];
    const float* bias   = (const float*)d_in[2];
    const float* w_om   = (const float*)d_in[3];
    const float* b_om   = (const float*)d_in[4];
    float* out = (float*)d_out;

    if (ws_size >= WS_FULL) {
        _Float16* tin  = (_Float16*)d_ws;
        _Float16* wt3h = (_Float16*)((char*)d_ws + WT3_OFF);
        _Float16* wmtA = (_Float16*)((char*)d_ws + WMTA_OFF);
        int total = WT3_ELEMS + WMTA_ELEMS;
        prep_w16<<<(total + 255) / 256, 256, 0, stream>>>(weight, w_om, wt3h, wmtA);
        prep_t<<<dim3(128, 8), 256, 0, stream>>>(input, tin);
        dim3 grid(2, 128, 8);
        dcn_hybrid11<<<grid, dim3(256, 1, 1), 0, stream>>>(tin, wt3h, wmtA, bias, b_om, out);
    } else if (ws_size >= WS_MID) {
        unsigned short* wt3 = (unsigned short*)d_ws;
        float* wmt = (float*)((char*)d_ws + (size_t)WT3_ELEMS * 2);
        int total = WT3_ELEMS + WMT_ELEMS;
        prep_w<<<(total + 255) / 256, 256, 0, stream>>>(weight, w_om, wt3, wmt);
        dim3 grid(2, 128, 8);
        dcn_hybrid7<<<grid, dim3(256, 1, 1), 0, stream>>>(input, wt3, bias, wmt, b_om, out);
    } else {
        dim3 grid(2, 32, 8);
        dcn_fb<<<grid, dim3(64, 4, 1), 0, stream>>>(input, weight, bias, w_om, b_om, out);
    }
}

// Round 13
// 151.997 us; speedup vs baseline: 1.3465x; 1.3465x over previous
//
#include <hip/hip_runtime.h>
#include <math.h>

#define HW (128*128)

typedef short short8 __attribute__((ext_vector_type(8)));
typedef float floatx4 __attribute__((ext_vector_type(4)));
typedef unsigned int uintx4 __attribute__((ext_vector_type(4)));
typedef _Float16 half2v __attribute__((ext_vector_type(2)));
typedef _Float16 half8v __attribute__((ext_vector_type(8)));

#define MFMA(a,b,c)   __builtin_amdgcn_mfma_f32_16x16x32_bf16((a),(b),(c),0,0,0)
#define MFMA16(a,b,c) __builtin_amdgcn_mfma_f32_16x16x32_f16((a),(b),(c),0,0,0)

union V16 { uintx4 u; half2v h2[4]; half8v h8; };

// ---------------- workspace layout ----------------
#define WT3_ELEMS   (9*3*4*64*8)         // [kk][ks][quad][o][i], c=ks*32+quad*8+i
#define WMTA_ELEMS  (19*2*4*16*8)        // [kt][n][quad][m15][i]
#define WMT_ELEMS   (594*27)             // MID tier fp32
#define TIN_BYTES   ((size_t)8*HW*64*2)  // 16 MB
#define WT3_OFF     TIN_BYTES
#define WMTA_OFF    (WT3_OFF + (size_t)WT3_ELEMS*2)
#define WS_FULL     (WMTA_OFF + (size_t)WMTA_ELEMS*2)
#define WS_MID      ((size_t)WT3_ELEMS*2 + (size_t)WMT_ELEMS*4)

static __device__ __forceinline__ unsigned short f2bf(float x) {
    unsigned u = __float_as_uint(x);
    unsigned r = u + 0x7FFFu + ((u >> 16) & 1u);
    return (unsigned short)(r >> 16);
}

static __device__ __forceinline__ unsigned cvt_pk_bf16(float lo, float hi) {
    unsigned r;
    asm("v_cvt_pk_bf16_f32 %0, %1, %2" : "=v"(r) : "v"(lo), "v"(hi));
    return r;
}

// ---------------- prep: fp16 weights (FULL tier) ----------------
__global__ __launch_bounds__(256) void prep_w16(
    const float* __restrict__ weight, const float* __restrict__ w_om,
    _Float16* __restrict__ wt3, _Float16* __restrict__ wmtA)
{
    int t = blockIdx.x * 256 + threadIdx.x;
    if (t < WT3_ELEMS) {
        int i = t & 7;  int u = t >> 3;
        int o = u & 63; u >>= 6;
        int quad = u & 3; u >>= 2;
        int ks = u % 3, kk = u / 3;
        int c = ks * 32 + quad * 8 + i;
        float v = (c < 66) ? weight[o * 594 + c * 9 + kk] : 0.0f;
        wt3[t] = (_Float16)v;
    } else if (t < WT3_ELEMS + WMTA_ELEMS) {
        int t2 = t - WT3_ELEMS;
        int i = t2 & 7;  int u = t2 >> 3;
        int m15 = u & 15; u >>= 4;
        int quad = u & 3; u >>= 2;
        int n = u & 1;    int kt = u >> 1;
        int o = 16 * n + m15;
        float v = 0.0f;
        if (o < 27) {
            if (kt < 18) {
                int j = kt >> 1, c = (kt & 1) * 32 + quad * 8 + i;
                v = w_om[o * 594 + c * 9 + j];
            } else {
                int q = quad * 8 + i;
                if (q < 18) {
                    int j = q >> 1, c = 64 + (q & 1);
                    v = w_om[o * 594 + c * 9 + j];
                }
            }
        }
        wmtA[t2] = (_Float16)v;
    }
}

// ---------------- prep: NCHW fp32 -> NHWC fp16 transpose ----------------
__global__ __launch_bounds__(256) void prep_t(
    const float* __restrict__ in, _Float16* __restrict__ t_out)
{
    __shared__ float s[64][129];
    const int y = blockIdx.x, b = blockIdx.y;
    const int tid = threadIdx.x, lane = tid & 63, w = tid >> 6;
    const float* src = in + (size_t)b * 64 * HW + y * 128;
#pragma unroll
    for (int i = 0; i < 16; ++i) {
        int c = w * 16 + i;
        s[c][lane]      = src[(size_t)c * HW + lane];
        s[c][lane + 64] = src[(size_t)c * HW + lane + 64];
    }
    __syncthreads();
    _Float16* dst = t_out + ((size_t)b * HW + (size_t)y * 128) * 64;
    const int c = lane, x0 = w * 32;
#pragma unroll
    for (int xx = 0; xx < 32; ++xx) {
        int x = x0 + xx;
        dst[(size_t)x * 64 + c] = (_Float16)s[c][x];
    }
}

// ---------------- prep: weights (bf16+fp32, MID tier) ----------------
__global__ __launch_bounds__(256) void prep_w(
    const float* __restrict__ weight, const float* __restrict__ w_om,
    unsigned short* __restrict__ wt3, float* __restrict__ wmt)
{
    int t = blockIdx.x * 256 + threadIdx.x;
    if (t < WT3_ELEMS) {
        int i = t & 7;  int u = t >> 3;
        int o = u & 63; u >>= 6;
        int quad = u & 3; u >>= 2;
        int ks = u % 3, kk = u / 3;
        int c = ks * 32 + quad * 8 + i;
        float v = (c < 66) ? weight[o * 594 + c * 9 + kk] : 0.0f;
        wt3[t] = f2bf(v);
    } else if (t < WT3_ELEMS + WMT_ELEMS) {
        int t2 = t - WT3_ELEMS;
        int oc = t2 % 27, ck = t2 / 27;
        wmt[t2] = w_om[oc * 594 + ck];
    }
}

// Round 2:  XCD-pinning remap (FETCH 268->18.5MB, verified).
// Round 6:  NHWC fp16 shadow input (274 -> 214us).
// Round 7:  Phase A on matrix cores (214 -> 171us).
// Round 10: spill fix (171 -> 119.6us).
// Round 12/13: L1/L2 GATHER-THROUGHPUT FIX (R12 never ran: broker timeout;
//   resubmitted unchanged). Line-request arithmetic: each gather instr
//   touches 16 distinct 128B lines (1 pixel = 1 line in NHWC); ~2k
//   lines/wave x 32 waves/CU = 64k line-deliveries/CU through L1 at
//   ~64B/cy, L1 thrashed (per-CU working set >> 32KB) -> most re-fetch from
//   L2 (~2GB aggregate = ~58us at 34.5TB/s). Explains flat 119us with all
//   pipes "idle". Fix: stage rows ho-2..ho+2 x cols wo0-2..wo0+65 (5x68
//   lines, 43.5KB fp16) in LDS once per block (coalesced); Phase A + Phase B
//   gathers become swizzled ds_read_b128 (chunk ^= col&7, even bank
//   spread). Arbitrary-offset correctness kept: per-tap __all(in-tile)
//   test falls back to the proven global-gather path. LDS 58.75KB ->
//   2 blocks/CU (throughput-bound, occupancy secondary).
__global__ __launch_bounds__(256, 2) void dcn_hybrid12(
    const _Float16* __restrict__ t_in,
    const _Float16* __restrict__ wt3h,
    const _Float16* __restrict__ wmtA,
    const float* __restrict__ bias,
    const float* __restrict__ b_om,
    float* __restrict__ out)
{
    // tile line (r,c) = image (clamp(ho-2+r), clamp(wo0-2+c)), 64ch fp16 =
    // 128B = 8 chunks of 16B; chunk k stored at slot k ^ (c&7).
    __shared__ __align__(16) unsigned short s_tile[5 * 68 * 64];       // 43520 B
    __shared__ float s_om[32 * 65];                                    // 8320 B
    __shared__ float s_offh[9 * 64], s_offw[9 * 64], s_maskf[9 * 64];  // 6912 B

    const int tid  = threadIdx.x;
    const int lane = tid & 63;
    const int w    = tid >> 6;
    const int wu   = __builtin_amdgcn_readfirstlane(w);
    const int m15  = lane & 15;
    const int quad = lane >> 4;

    // ---- XCD-pinning remap
    const int L   = blockIdx.x + 2 * (blockIdx.y + 128 * blockIdx.z);
    const int b   = L & 7;
    const int r   = L >> 3;
    const int ho  = r >> 1;
    const int wo0 = (r & 1) * 64;

    const float invH = 1.0f / 128.0f;

    const int pixL = wu * 16 + m15;
    const int wob  = wo0 + pixL;

    const _Float16* tinb = t_in + (size_t)b * HW * 64;
    const _Float16* tinq = tinb + quad * 8;     // global-fallback base

    // ---------------- stage the tile (coalesced, once) ----------------
    for (int Lt = tid; Lt < 340; Lt += 256) {
        int rt = Lt / 68, ct = Lt - rt * 68;
        int gy = min(max(ho - 2 + rt, 0), 127);
        int gx = min(max(wo0 - 2 + ct, 0), 127);
        const uintx4* src = (const uintx4*)(tinb + ((size_t)gy * 128 + gx) * 64);
        uintx4* dst = (uintx4*)&s_tile[(size_t)Lt * 64];
        int sw = ct & 7;
#pragma unroll
        for (int k = 0; k < 8; ++k)
            dst[k ^ sw] = src[k];
    }

    // tile read: logical 16B chunk q (0..7) of tile line (rt, ct)
    auto tileread = [&](int rt, int ct, int q) -> uintx4 {
        return *(const uintx4*)&s_tile[(((rt * 68 + ct) << 3) + (q ^ (ct & 7))) << 3];
    };

    // ---- 9 fixed-tap tile coords / validity for pixel (ho, wob)
    int   tr9[9], tc9[9];
    float ok9[9];
#pragma unroll
    for (int j = 0; j < 9; ++j) {
        int y = ho - 1 + j / 3;
        int x = wob - 1 + j % 3;
        bool ok = ((unsigned)y < 128u) && ((unsigned)x < 128u);
        int yc = min(max(y, 0), 127), xc = min(max(x, 0), 127);
        tr9[j] = yc - (ho - 2);          // in [0,5)  (proven in-range)
        tc9[j] = xc - (wo0 - 2);         // in [0,68)
        ok9[j] = ok ? 1.0f : 0.0f;
    }
    __syncthreads();   // tile staged

    // ---------------- Phase A: offset conv via f16 MFMA (tile reads) ------
    floatx4 a0 = (floatx4){0.f, 0.f, 0.f, 0.f};
    floatx4 a1 = (floatx4){0.f, 0.f, 0.f, 0.f};

#pragma unroll
    for (int j = 0; j < 9; ++j) {
        _Float16 okh = (_Float16)ok9[j];
        half2v okh2 = {okh, okh};
#pragma unroll
        for (int h = 0; h < 2; ++h) {
            V16 bb;
            bb.u = tileread(tr9[j], tc9[j], 4 * h + quad);
#pragma unroll
            for (int rr = 0; rr < 4; ++rr) bb.h2[rr] = bb.h2[rr] * okh2;
            const int kt = j * 2 + h;
            const _Float16* ap = wmtA + (size_t)((kt * 2) * 4 + quad) * 128 + m15 * 8;
            half8v A0 = *(const half8v*)ap;
            half8v A1 = *(const half8v*)(ap + 512);
            a0 = MFMA16(A0, bb.h8, a0);
            a1 = MFMA16(A1, bb.h8, a1);
        }
    }
    {   // coord K-tile (kt=18)
        V16 bb;
#pragma unroll
        for (int rr = 0; rr < 4; ++rr) {
            float ve = 0.f, vo = 0.f;
            int j = quad * 4 + rr;
            if (j < 9) {
                int y = ho - 1 + j / 3;
                int x = wob - 1 + j % 3;
                bool ok = ((unsigned)y < 128u) && ((unsigned)x < 128u);
                ve = ok ? y * invH : 0.f;
                vo = ok ? (x * invH - 0.5f) : 0.f;
            }
            bb.h2[rr] = (half2v){(_Float16)ve, (_Float16)vo};
        }
        const _Float16* ap = wmtA + (size_t)((18 * 2) * 4 + quad) * 128 + m15 * 8;
        half8v A0 = *(const half8v*)ap;
        half8v A1 = *(const half8v*)(ap + 512);
        a0 = MFMA16(A0, bb.h8, a0);
        a1 = MFMA16(A1, bb.h8, a1);
    }

    // stage om to LDS: s_om[oc][pix]
#pragma unroll
    for (int rr = 0; rr < 4; ++rr) {
        s_om[(quad * 4 + rr) * 65 + pixL]      = a0[rr];
        s_om[(16 + quad * 4 + rr) * 65 + pixL] = a1[rr];
    }
    __syncthreads();

    // ---- idx/mask epilogue (nt stores) + fp32 offsets/mask into LDS
    {
        float* out_idx = out + (size_t)8 * 64 * HW;
        float* out_msk = out_idx + (size_t)8 * 18 * HW;
        const int wo = wo0 + lane;
        const int p  = ho * 128 + wo;
        const float hg = ho * invH;
        const float wg = wo * invH - 0.5f;
        int oc0 = wu * 7;
        int noc = (wu == 3) ? 6 : 7;
        for (int t = 0; t < noc; ++t) {
            int oc = oc0 + t;
            float s = b_om[oc] + s_om[oc * 65 + lane];
            if (oc < 9) {
                __builtin_nontemporal_store(hg + (float)(oc / 3 - 1) + s,
                    &out_idx[((size_t)b * 18 + oc) * HW + p]);
                if (oc & 1) s_offw[(oc >> 1) * 64 + lane] = s;
                else        s_offh[(oc >> 1) * 64 + lane] = s;
            } else if (oc < 18) {
                __builtin_nontemporal_store(wg + (float)((oc - 9) % 3 - 1) + s,
                    &out_idx[((size_t)b * 18 + oc) * HW + p]);
                if (oc & 1) s_offw[(oc >> 1) * 64 + lane] = s;
                else        s_offh[(oc >> 1) * 64 + lane] = s;
            } else {
                float mkv = 1.0f / (1.0f + __expf(-s));
                __builtin_nontemporal_store(mkv,
                    &out_msk[((size_t)b * 9 + (oc - 18)) * HW + p]);
                s_maskf[(oc - 18) * 64 + lane] = mkv;
            }
        }
    }
    __syncthreads();   // offsets/mask ready

    // ---------------- Phase B: tile ds_reads + f16 MFMA -------------------
    floatx4 acc[4];
#pragma unroll
    for (int t = 0; t < 4; ++t) acc[t] = (floatx4){0.f, 0.f, 0.f, 0.f};

    const int hom1 = ho - 1;

#pragma unroll
    for (int kk = 0; kk < 9; ++kk) {
        float offh = s_offh[kk * 64 + pixL];
        float offw = s_offw[kk * 64 + pixL];
        float mval = s_maskf[kk * 64 + pixL];

        float ph = offh + (float)(kk / 3) + (float)hom1;
        float pw = offw + (float)(kk % 3) + (float)(wob - 1);
        float h0f = floorf(ph), w0f = floorf(pw);
        int h0 = (int)h0f, w0 = (int)w0f;
        int h1 = h0 + 1, w1 = w0 + 1;
        float lh = ph - h0f, lw = pw - w0f;
        float hh = 1.0f - lh, hwp = 1.0f - lw;
        bool okh0 = (unsigned)h0 < 128u, okh1 = (unsigned)h1 < 128u;
        bool okw0 = (unsigned)w0 < 128u, okw1 = (unsigned)w1 < 128u;
        float w00 = (okh0 && okw0) ? hh * hwp * mval : 0.0f;
        float w01 = (okh0 && okw1) ? hh * lw  * mval : 0.0f;
        float w10 = (okh1 && okw0) ? lh * hwp * mval : 0.0f;
        float w11 = (okh1 && okw1) ? lh * lw  * mval : 0.0f;
        int h0c = min(max(h0, 0), 127), h1c = min(max(h1, 0), 127);
        int w0c = min(max(w0, 0), 127), w1c = min(max(w1, 0), 127);

        int r0 = h0c - (ho - 2), r1 = h1c - (ho - 2);
        int c0 = w0c - (wo0 - 2), c1 = w1c - (wo0 - 2);
        bool intile = ((unsigned)r0 < 5u) && ((unsigned)r1 < 5u)
                   && ((unsigned)c0 < 68u) && ((unsigned)c1 < 68u);

        V16 A00, A01, A10, A11, B00, B01, B10, B11;
        if (__all(intile)) {
            A00.u = tileread(r0, c0, quad);     A01.u = tileread(r0, c1, quad);
            A10.u = tileread(r1, c0, quad);     A11.u = tileread(r1, c1, quad);
            B00.u = tileread(r0, c0, quad + 4); B01.u = tileread(r0, c1, quad + 4);
            B10.u = tileread(r1, c0, quad + 4); B11.u = tileread(r1, c1, quad + 4);
        } else {
            int o00 = h0c * 128 + w0c, o01 = h0c * 128 + w1c;
            int o10 = h1c * 128 + w0c, o11 = h1c * 128 + w1c;
            A00.u = *(const uintx4*)(tinq + (size_t)o00 * 64);
            A01.u = *(const uintx4*)(tinq + (size_t)o01 * 64);
            A10.u = *(const uintx4*)(tinq + (size_t)o10 * 64);
            A11.u = *(const uintx4*)(tinq + (size_t)o11 * 64);
            B00.u = *(const uintx4*)(tinq + (size_t)o00 * 64 + 32);
            B01.u = *(const uintx4*)(tinq + (size_t)o01 * 64 + 32);
            B10.u = *(const uintx4*)(tinq + (size_t)o10 * 64 + 32);
            B11.u = *(const uintx4*)(tinq + (size_t)o11 * 64 + 32);
        }

        _Float16 h00 = (_Float16)w00, h01 = (_Float16)w01;
        _Float16 h10 = (_Float16)w10, h11 = (_Float16)w11;
        half2v W00 = {h00, h00}, W01 = {h01, h01};
        half2v W10 = {h10, h10}, W11 = {h11, h11};

        V16 b0, b1, b2;
#pragma unroll
        for (int rr = 0; rr < 4; ++rr) {
            b0.h2[rr] = A00.h2[rr] * W00 + A01.h2[rr] * W01
                      + A10.h2[rr] * W10 + A11.h2[rr] * W11;
            b1.h2[rr] = B00.h2[rr] * W00 + B01.h2[rr] * W01
                      + B10.h2[rr] * W10 + B11.h2[rr] * W11;
        }
        float c64 = (w00 + w01) * (h0c * invH) + (w10 + w11) * (h1c * invH);
        float c65 = (w00 + w10) * (w0c * invH - 0.5f) + (w01 + w11) * (w1c * invH - 0.5f);
        b2.u = (uintx4){0u, 0u, 0u, 0u};
        if (quad == 0) b2.h2[0] = (half2v){(_Float16)c64, (_Float16)c65};

        const _Float16* w0p = wt3h + (size_t)(kk * 3) * 2048 + quad * 512;
        const _Float16* w1p = w0p + 2048;
        const _Float16* w2p = w0p + 4096;
#pragma unroll
        for (int t = 0; t < 4; ++t) {
            int o8 = (16 * t + m15) * 8;
            half8v A0 = *(const half8v*)&w0p[o8];
            half8v A1 = *(const half8v*)&w1p[o8];
            half8v A2 = *(const half8v*)&w2p[o8];
            acc[t] = MFMA16(A0, b0.h8, acc[t]);
            acc[t] = MFMA16(A1, b1.h8, acc[t]);
            acc[t] = MFMA16(A2, b2.h8, acc[t]);
        }
    }

    // ---------- epilogue: LDS redistribute -> full-line nt stores ------
    {
        const size_t rowbase = (size_t)b * 64 * HW + (size_t)ho * 128 + wo0;
        __syncthreads();
#pragma unroll
        for (int t = 0; t < 2; ++t)
#pragma unroll
            for (int rr = 0; rr < 4; ++rr)
                s_om[(16 * t + quad * 4 + rr) * 65 + pixL] = acc[t][rr];
        __syncthreads();
#pragma unroll
        for (int k = 0; k < 8; ++k) {
            int o = wu * 8 + k;
            float v = s_om[o * 65 + lane] + bias[o];
            __builtin_nontemporal_store(v, &out[(size_t)o * HW + rowbase + lane]);
        }
        __syncthreads();
#pragma unroll
        for (int t = 0; t < 2; ++t)
#pragma unroll
            for (int rr = 0; rr < 4; ++rr)
                s_om[(16 * t + quad * 4 + rr) * 65 + pixL] = acc[2 + t][rr];
        __syncthreads();
#pragma unroll
        for (int k = 0; k < 8; ++k) {
            int o = 32 + wu * 8 + k;
            float v = s_om[(o - 32) * 65 + lane] + bias[o];
            __builtin_nontemporal_store(v, &out[(size_t)o * HW + rowbase + lane]);
        }
    }
}

// ---------------- MID tier: R5 kernel (verified), bf16 MFMA ----------------
__global__ __launch_bounds__(256, 4) void dcn_hybrid7(
    const float* __restrict__ input,
    const unsigned short* __restrict__ wt3,
    const float* __restrict__ bias,
    const float* __restrict__ wmt,
    const float* __restrict__ b_om,
    float* __restrict__ out)
{
    __shared__ float s_red[4 * 27 * 64];
    __shared__ float s_offh[9 * 64], s_offw[9 * 64], s_maskf[9 * 64];

    const int tid  = threadIdx.x;
    const int lane = tid & 63;
    const int w    = tid >> 6;
    const int wu   = __builtin_amdgcn_readfirstlane(w);
    const int m15  = lane & 15;
    const int quad = lane >> 4;

    const int L   = blockIdx.x + 2 * (blockIdx.y + 128 * blockIdx.z);
    const int b   = L & 7;
    const int r   = L >> 3;
    const int ho  = r >> 1;
    const int wo0 = (r & 1) * 64;

    const int wo  = wo0 + lane;
    const int p   = ho * 128 + wo;
    const float invH = 1.0f / 128.0f;

    const float* inb = input + (size_t)b * 64 * HW;

    int   a9[9];
    float okf[9], vy[9], vx[9];
#pragma unroll
    for (int j = 0; j < 9; ++j) {
        int y = ho - 1 + j / 3;
        int x = wo - 1 + j % 3;
        bool ok = ((unsigned)y < 128u) && ((unsigned)x < 128u);
        int yc = min(max(y, 0), 127), xc = min(max(x, 0), 127);
        a9[j]  = yc * 128 + xc;
        okf[j] = ok ? 1.0f : 0.0f;
        vy[j]  = ok ? y * invH : 0.0f;
        vx[j]  = ok ? (x * invH - 0.5f) : 0.0f;
    }

    const int nc = (wu < 2) ? 17 : 16;

    float om_part[27];
#pragma unroll
    for (int oc = 0; oc < 27; ++oc) om_part[oc] = 0.0f;

    {
        float va[9], vb[9];
        {
            const float* pc = inb + wu * HW;
#pragma unroll
            for (int j = 0; j < 9; ++j) va[j] = pc[a9[j]] * okf[j];
        }
        for (int i = 0; i < nc; ++i) {
            int c = wu + 4 * i;
            if (i + 1 < nc) {
                int cn = c + 4;
                if (cn < 64) {
                    const float* pc = inb + cn * HW;
#pragma unroll
                    for (int j = 0; j < 9; ++j) vb[j] = pc[a9[j]] * okf[j];
                } else if (cn == 64) {
#pragma unroll
                    for (int j = 0; j < 9; ++j) vb[j] = vy[j];
                } else {
#pragma unroll
                    for (int j = 0; j < 9; ++j) vb[j] = vx[j];
                }
            }
#pragma unroll
            for (int j = 0; j < 9; ++j) {
                const float* wp = wmt + (c * 9 + j) * 27;
#pragma unroll
                for (int oc = 0; oc < 27; ++oc)
                    om_part[oc] = fmaf(va[j], wp[oc], om_part[oc]);
            }
#pragma unroll
            for (int j = 0; j < 9; ++j) va[j] = vb[j];
        }
    }
#pragma unroll
    for (int oc = 0; oc < 27; ++oc)
        s_red[(w * 27 + oc) * 64 + lane] = om_part[oc];
    __syncthreads();

    {
        float* out_idx = out + (size_t)8 * 64 * HW;
        float* out_msk = out_idx + (size_t)8 * 18 * HW;
        const float hg = ho * invH;
        const float wg = wo * invH - 0.5f;
        int oc0 = wu * 7;
        int noc = (wu == 3) ? 6 : 7;
        for (int t = 0; t < noc; ++t) {
            int oc = oc0 + t;
            float s = b_om[oc]
                    + s_red[(0 * 27 + oc) * 64 + lane]
                    + s_red[(1 * 27 + oc) * 64 + lane]
                    + s_red[(2 * 27 + oc) * 64 + lane]
                    + s_red[(3 * 27 + oc) * 64 + lane];
            if (oc < 9) {
                out_idx[((size_t)b * 18 + oc) * HW + p] = hg + (float)(oc / 3 - 1) + s;
                if (oc & 1) s_offw[(oc >> 1) * 64 + lane] = s;
                else        s_offh[(oc >> 1) * 64 + lane] = s;
            } else if (oc < 18) {
                out_idx[((size_t)b * 18 + oc) * HW + p] = wg + (float)((oc - 9) % 3 - 1) + s;
                if (oc & 1) s_offw[(oc >> 1) * 64 + lane] = s;
                else        s_offh[(oc >> 1) * 64 + lane] = s;
            } else {
                float mkv = 1.0f / (1.0f + __expf(-s));
                out_msk[((size_t)b * 9 + (oc - 18)) * HW + p] = mkv;
                s_maskf[(oc - 18) * 64 + lane] = mkv;
            }
        }
    }
    __syncthreads();

    const int pixL = wu * 16 + m15;
    const int wob  = wo0 + pixL;
    const int hom1 = ho - 1;

    floatx4 acc[4];
#pragma unroll
    for (int t = 0; t < 4; ++t) acc[t] = (floatx4){0.f, 0.f, 0.f, 0.f};

    const float* base0 = inb + (size_t)(quad * 8) * HW;
    const float* base1 = base0 + (size_t)32 * HW;

#pragma unroll
    for (int kk = 0; kk < 9; ++kk) {
        float offh = s_offh[kk * 64 + pixL];
        float offw = s_offw[kk * 64 + pixL];
        float mval = s_maskf[kk * 64 + pixL];

        float ph = offh + (float)(kk / 3) + (float)hom1;
        float pw = offw + (float)(kk % 3) + (float)(wob - 1);
        float h0f = floorf(ph), w0f = floorf(pw);
        int h0 = (int)h0f, w0 = (int)w0f;
        int h1 = h0 + 1, w1 = w0 + 1;
        float lh = ph - h0f, lw = pw - w0f;
        float hh = 1.0f - lh, hwp = 1.0f - lw;
        bool okh0 = (unsigned)h0 < 128u, okh1 = (unsigned)h1 < 128u;
        bool okw0 = (unsigned)w0 < 128u, okw1 = (unsigned)w1 < 128u;
        float w00 = (okh0 && okw0) ? hh * hwp * mval : 0.0f;
        float w01 = (okh0 && okw1) ? hh * lw  * mval : 0.0f;
        float w10 = (okh1 && okw0) ? lh * hwp * mval : 0.0f;
        float w11 = (okh1 && okw1) ? lh * lw  * mval : 0.0f;
        int h0c = min(max(h0, 0), 127), h1c = min(max(h1, 0), 127);
        int w0c = min(max(w0, 0), 127), w1c = min(max(w1, 0), 127);
        int o00 = h0c * 128 + w0c, o01 = h0c * 128 + w1c;
        int o10 = h1c * 128 + w0c, o11 = h1c * 128 + w1c;

        unsigned pk0[4], pk1[4];
#pragma unroll
        for (int j = 0; j < 4; ++j) {
            const float* pa = base0 + (size_t)(2 * j) * HW;
            const float* pb = pa + HW;
            float ca = w00 * pa[o00] + w01 * pa[o01] + w10 * pa[o10] + w11 * pa[o11];
            float cb = w00 * pb[o00] + w01 * pb[o01] + w10 * pb[o10] + w11 * pb[o11];
            pk0[j] = cvt_pk_bf16(ca, cb);
            const float* pa1 = base1 + (size_t)(2 * j) * HW;
            const float* pb1 = pa1 + HW;
            float ca1 = w00 * pa1[o00] + w01 * pa1[o01] + w10 * pa1[o10] + w11 * pa1[o11];
            float cb1 = w00 * pb1[o00] + w01 * pb1[o01] + w10 * pb1[o10] + w11 * pb1[o11];
            pk1[j] = cvt_pk_bf16(ca1, cb1);
        }
        union { uintx4 u; short8 s; } b0, b1, b2;
        b0.u = (uintx4){pk0[0], pk0[1], pk0[2], pk0[3]};
        b1.u = (uintx4){pk1[0], pk1[1], pk1[2], pk1[3]};
        float c64 = (w00 + w01) * (h0c * invH) + (w10 + w11) * (h1c * invH);
        float c65 = (w00 + w10) * (w0c * invH - 0.5f) + (w01 + w11) * (w1c * invH - 0.5f);
        unsigned pk2 = (quad == 0) ? cvt_pk_bf16(c64, c65) : 0u;
        b2.u = (uintx4){pk2, 0u, 0u, 0u};

        const unsigned short* w0p = wt3 + (size_t)(kk * 3 + 0) * 2048 + quad * 512;
        const unsigned short* w1p = w0p + 2048;
        const unsigned short* w2p = w0p + 4096;
#pragma unroll
        for (int t = 0; t < 4; ++t) {
            int o8 = (16 * t + m15) * 8;
            short8 A0 = *(const short8*)&w0p[o8];
            short8 A1 = *(const short8*)&w1p[o8];
            short8 A2 = *(const short8*)&w2p[o8];
            acc[t] = MFMA(A0, b0.s, acc[t]);
            acc[t] = MFMA(A1, b1.s, acc[t]);
            acc[t] = MFMA(A2, b2.s, acc[t]);
        }
    }

    {
        size_t pb = (size_t)ho * 128 + wob;
#pragma unroll
        for (int t = 0; t < 4; ++t) {
#pragma unroll
            for (int rr = 0; rr < 4; ++rr) {
                int o = 16 * t + quad * 4 + rr;
                out[((size_t)b * 64 + o) * HW + pb] = acc[t][rr] + bias[o];
            }
        }
    }
}

// ------------------- fallback (no workspace): fp32 baseline -------------------
__global__ __launch_bounds__(256) void dcn_fb(
    const float* __restrict__ input,
    const float* __restrict__ wmain,
    const float* __restrict__ bias,
    const float* __restrict__ wom,
    const float* __restrict__ b_om,
    float* __restrict__ out)
{
    const int wo = blockIdx.x * 64 + threadIdx.x;
    const int ho = blockIdx.y * 4 + threadIdx.y;
    const int b  = blockIdx.z;
    const int p  = ho * 128 + wo;
    const float invH = 1.0f / 128.0f;
    const float* inb = input + (size_t)b * 64 * HW;

    float om[27];
#pragma unroll
    for (int oc = 0; oc < 27; ++oc) om[oc] = b_om[oc];

    for (int c = 0; c < 64; ++c) {
        const float* pc = inb + c * HW;
        float v[9];
#pragma unroll
        for (int kh = 0; kh < 3; ++kh) {
            int y = ho - 1 + kh;
            bool oky = (unsigned)y < 128u;
#pragma unroll
            for (int kw = 0; kw < 3; ++kw) {
                int x = wo - 1 + kw;
                bool ok = oky && ((unsigned)x < 128u);
                v[kh*3+kw] = ok ? pc[y * 128 + x] : 0.0f;
            }
        }
#pragma unroll
        for (int oc = 0; oc < 27; ++oc)
#pragma unroll
            for (int i = 0; i < 9; ++i)
                om[oc] = fmaf(v[i], wom[oc*594 + c*9 + i], om[oc]);
    }
    {
        float v64[9], v65[9];
#pragma unroll
        for (int kh = 0; kh < 3; ++kh) {
            int y = ho - 1 + kh;
            bool oky = (unsigned)y < 128u;
#pragma unroll
            for (int kw = 0; kw < 3; ++kw) {
                int x = wo - 1 + kw;
                bool ok = oky && ((unsigned)x < 128u);
                v64[kh*3+kw] = ok ? y * invH : 0.0f;
                v65[kh*3+kw] = ok ? (x * invH - 0.5f) : 0.0f;
            }
        }
#pragma unroll
        for (int oc = 0; oc < 27; ++oc)
#pragma unroll
            for (int i = 0; i < 9; ++i) {
                om[oc] = fmaf(v64[i], wom[oc*594 + 64*9 + i], om[oc]);
                om[oc] = fmaf(v65[i], wom[oc*594 + 65*9 + i], om[oc]);
            }
    }

    const float hg = ho * invH;
    const float wg = wo * invH - 0.5f;
    float* out_idx = out + (size_t)8 * 64 * HW;
    float* out_msk = out_idx + (size_t)8 * 18 * HW;
#pragma unroll
    for (int cc = 0; cc < 9; ++cc)
        out_idx[((size_t)b*18 + cc)*HW + p] = hg + (float)(cc/3 - 1) + om[cc];
#pragma unroll
    for (int cc = 9; cc < 18; ++cc)
        out_idx[((size_t)b*18 + cc)*HW + p] = wg + (float)((cc-9)%3 - 1) + om[cc];

    float mk[9];
#pragma unroll
    for (int kk = 0; kk < 9; ++kk) {
        mk[kk] = 1.0f / (1.0f + __expf(-om[18+kk]));
        out_msk[((size_t)b*9 + kk)*HW + p] = mk[kk];
    }

    float acc[64];
#pragma unroll
    for (int o = 0; o < 64; ++o) acc[o] = bias[o];

#pragma unroll
    for (int kk = 0; kk < 9; ++kk) {
        float ph = om[2*kk]   + (float)(kk/3) + (float)(ho - 1);
        float pw = om[2*kk+1] + (float)(kk%3) + (float)(wo - 1);
        float h0f = floorf(ph), w0f = floorf(pw);
        int h0 = (int)h0f, w0 = (int)w0f;
        int h1 = h0 + 1, w1 = w0 + 1;
        float lh = ph - h0f, lw = pw - w0f;
        float hh = 1.0f - lh, hwp = 1.0f - lw;
        float m = mk[kk];
        bool okh0 = (unsigned)h0 < 128u, okh1 = (unsigned)h1 < 128u;
        bool okw0 = (unsigned)w0 < 128u, okw1 = (unsigned)w1 < 128u;
        float w00 = (okh0 && okw0) ? hh*hwp*m : 0.0f;
        float w01 = (okh0 && okw1) ? hh*lw*m  : 0.0f;
        float w10 = (okh1 && okw0) ? lh*hwp*m : 0.0f;
        float w11 = (okh1 && okw1) ? lh*lw*m  : 0.0f;
        int h0c = min(max(h0, 0), 127), h1c = min(max(h1, 0), 127);
        int w0c = min(max(w0, 0), 127), w1c = min(max(w1, 0), 127);
        int o00 = h0c*128 + w0c, o01 = h0c*128 + w1c;
        int o10 = h1c*128 + w0c, o11 = h1c*128 + w1c;

        for (int c = 0; c < 64; ++c) {
            const float* pc = inb + c * HW;
            float col = w00*pc[o00] + w01*pc[o01] + w10*pc[o10] + w11*pc[o11];
#pragma unroll
            for (int o = 0; o < 64; ++o)
                acc[o] = fmaf(col, wmain[o*594 + c*9 + kk], acc[o]);
        }
        {
            float y0 = h0c * invH, y1 = h1c * invH;
            float x0 = w0c * invH - 0.5f, x1 = w1c * invH - 0.5f;
            float col64 = (w00 + w01)*y0 + (w10 + w11)*y1;
            float col65 = (w00 + w10)*x0 + (w01 + w11)*x1;
#pragma unroll
            for (int o = 0; o < 64; ++o) {
                acc[o] = fmaf(col64, wmain[o*594 + 64*9 + kk], acc[o]);
                acc[o] = fmaf(col65, wmain[o*594 + 65*9 + kk], acc[o]);
            }
        }
    }

#pragma unroll
    for (int o = 0; o < 64; ++o)
        out[((size_t)b*64 + o)*HW + p] = acc[o];
}

extern "C" void kernel_launch(void* const* d_in, const int* in_sizes, int n_in,
                              void* d_out, int out_size, void* d_ws, size_t ws_size,
                              hipStream_t stream)
{
    const float* input  = (const float*)d_in[0];
    const float* weight = (const float*)d_in[1];
    const float* bias   = (const float*)d_in[2];
    const float* w_om   = (const float*)d_in[3];
    const float* b_om   = (const float*)d_in[4];
    float* out = (float*)d_out;

    if (ws_size >= WS_FULL) {
        _Float16* tin  = (_Float16*)d_ws;
        _Float16* wt3h = (_Float16*)((char*)d_ws + WT3_OFF);
        _Float16* wmtA = (_Float16*)((char*)d_ws + WMTA_OFF);
        int total = WT3_ELEMS + WMTA_ELEMS;
        prep_w16<<<(total + 255) / 256, 256, 0, stream>>>(weight, w_om, wt3h, wmtA);
        prep_t<<<dim3(128, 8), 256, 0, stream>>>(input, tin);
        dim3 grid(2, 128, 8);
        dcn_hybrid12<<<grid, dim3(256, 1, 1), 0, stream>>>(tin, wt3h, wmtA, bias, b_om, out);
    } else if (ws_size >= WS_MID) {
        unsigned short* wt3 = (unsigned short*)d_ws;
        float* wmt = (float*)((char*)d_ws + (size_t)WT3_ELEMS * 2);
        int total = WT3_ELEMS + WMT_ELEMS;
        prep_w<<<(total + 255) / 256, 256, 0, stream>>>(weight, w_om, wt3, wmt);
        dim3 grid(2, 128, 8);
        dcn_hybrid7<<<grid, dim3(256, 1, 1), 0, stream>>>(input, wt3, bias, wmt, b_om, out);
    } else {
        dim3 grid(2, 32, 8);
        dcn_fb<<<grid, dim3(64, 4, 1), 0, stream>>>(input, weight, bias, w_om, b_om, out);
    }
}